// Round 7
// baseline (325.626 us; speedup 1.0000x reference)
//
#include <hip/hip_runtime.h>
#include <stdint.h>

#define NB 8
#define NP 100
#define NT 500
#define NV 128
#define NBP 800   // NB*NP
#define TILE 4

typedef unsigned long long u64;

// rotl via single v_alignbit_b32: alignbit(x,x,32-r) = rotr(x,32-r) = rotl(x,r)
#define ROTL(x, r) __builtin_amdgcn_alignbit((x), (x), 32 - (r))

// ---------------- Threefry-2x32, key = (0,1) (jax.random.key(1)) ----------------
__device__ __forceinline__ uint32_t threefry01_lo(uint32_t x0, uint32_t x1) {
  const uint32_t k0 = 0u, k1 = 1u;
  const uint32_t k2 = 0x1BD11BDAu ^ k0 ^ k1;  // 0x1BD11BDB
  x0 += k0; x1 += k1;
#define TF_R(r) { x0 += x1; x1 = ROTL(x1, r); x1 ^= x0; }
  TF_R(13) TF_R(15) TF_R(26) TF_R(6)
  x0 += k1; x1 += k2 + 1u;
  TF_R(17) TF_R(29) TF_R(16) TF_R(24)
  x0 += k2; x1 += k0 + 2u;
  TF_R(13) TF_R(15) TF_R(26) TF_R(6)
  x0 += k0; x1 += k1 + 3u;
  TF_R(17) TF_R(29) TF_R(16) TF_R(24)
  x0 += k1; x1 += k2 + 4u;
  TF_R(13) TF_R(15) TF_R(26) TF_R(6)
  x1 += k0 + 5u;            // o0 is dead — only the low word is used
#undef TF_R
  return x1;
}

// ---------------- Kernel 1: Gumbel sampling + serial argmin over V=128 ---------
// argmax_v(0.5*e + g_v)  ==  argmin_v((-log2 u_v) * exp(-0.5*e_v))
// Flat item grid: item = (row R = b*NT+t) * 50 + pp, thread handles paths
// (2pp, 2pp+1) of row R -> ILP-2 threefry chains, one snw ds_read per v.
// 1-wave blocks (64 thr), 3125 blocks -> fine-grained CU packing, ~6% tail.
__global__ __launch_bounds__(64) void k_sample(
    const float* __restrict__ em, const int* __restrict__ elen,
    int2* __restrict__ tl) {
  __shared__ float se[3][NV + 1];   // +1 pad: bank varies with row
  __shared__ float snw[3][NV + 1];  // -exp2(e * -0.5*log2e)
  const int tid = threadIdx.x;
  const int g0 = blockIdx.x * 64;
  const int R0 = g0 / 50;
  // stage rows R0..R0+2 (a 64-item block spans at most 3 rows)
  for (int i = tid; i < 3 * NV; i += 64) {
    const int r = i >> 7, v = i & 127;
    int R = R0 + r; R = R < NB * NT ? R : NB * NT - 1;
    const float e = em[(size_t)R * NV + v];
    se[r][v] = e;
    snw[r][v] = -__builtin_amdgcn_exp2f(e * -0.7213475204444817f);
  }
  __syncthreads();
  const int g = g0 + tid;
  const int R = g / 50;
  const int pp = g - R * 50;
  const int b = R / NT;
  const int t = R - b * NT;
  if (t >= elen[b]) return;  // frames beyond length are never consumed
  const int r = R - R0;
  const uint32_t base0 = (uint32_t)((b * NP + 2 * pp) * NT + t) << 7;  // *NV
  const uint32_t base1 = base0 + (uint32_t)(NT << 7);                  // p+1
  const float span = (float)(1.0 - 1e-6) - 1e-6f;
  float best0 = 3.0e38f, best1 = 3.0e38f;
  int bi0 = 0, bi1 = 0;
#pragma unroll 8
  for (int v = 0; v < NV; v++) {
    // partitionable threefry: bits[i] = low output of threefry(key, i>>32, i)
    const uint32_t r0 = threefry01_lo(0u, base0 + (uint32_t)v);
    const uint32_t r1 = threefry01_lo(0u, base1 + (uint32_t)v);
    // exact bits->u chain (unchanged numerics vs passing rounds)
    const float f0 = __uint_as_float((r0 >> 9) | 0x3f800000u) - 1.0f;
    const float f1 = __uint_as_float((r1 >> 9) | 0x3f800000u) - 1.0f;
    const float u0 = fmaxf(1e-6f, fmaf(f0, span, 1e-6f));
    const float u1 = fmaxf(1e-6f, fmaf(f1, span, 1e-6f));
    const float w = snw[r][v];
    const float s0 = __log2f(u0) * w;  // (-log2 u) * exp(-e/2) > 0
    const float s1 = __log2f(u1) * w;
    if (s0 < best0) { best0 = s0; bi0 = v; }  // strict < = first-index tiebreak
    if (s1 < best1) { best1 = s1; bi1 = v; }
  }
  const int ob = t * NBP + b * NP + 2 * pp;
  tl[ob]     = make_int2(bi0, __float_as_int(se[r][bi0]));
  tl[ob + 1] = make_int2(bi1, __float_as_int(se[r][bi1]));
}

// ---------------- Kernel 2: CTC collapse + Myers bit-parallel edit distance ----
// one block per b (8 x 64), thread = TWO paths (lane, lane+50) -> two
// independent Myers chains interleave (ILP-2 hides the 4cy dep latency).
// peq as 4 u32 planes (bank = c%32). TILE=4, double-buffered, 2 tiles ahead.
struct DpState {
  u64 Pv0, Pv1, Mv0, Mv1;
  int score, prev;
  double logp;
};

struct Ext {
  int cc[TILE];
  float ll[TILE];
  u64 eq0[TILE], eq1[TILE];
};

__device__ __forceinline__ void load4(int2 (&buf)[TILE], int tile,
                                      const int2* __restrict__ tl, int bpc) {
#pragma unroll
  for (int i = 0; i < TILE; i++) {
    int t = tile * TILE + i;
    t = t < NT ? t : NT - 1;
    buf[i] = tl[t * NBP + bpc];
  }
}

__device__ __forceinline__ void extract4(const int2 (&buf)[TILE],
                                         const uint32_t (*pq)[NV], Ext& e) {
#pragma unroll
  for (int i = 0; i < TILE; i++) {
    e.cc[i] = buf[i].x;
    e.ll[i] = __int_as_float(buf[i].y);
    const int c = buf[i].x & 127;
    e.eq0[i] = (u64)pq[0][c] | ((u64)pq[1][c] << 32);
    e.eq1[i] = (u64)pq[2][c] | ((u64)pq[3][c] << 32);
  }
}

__device__ __forceinline__ void proc4(const Ext& e, int tile, int myel,
                                      int hw, u64 hmask, DpState& st) {
#pragma unroll
  for (int i = 0; i < TILE; i++) {
    const int t = tile * TILE + i;
    if (t >= myel) break;  // uniform per block
    const int c = e.cc[i];
    const bool kept = (c != 0) && (c != st.prev);
    st.logp += (double)e.ll[i];
    st.prev = c;
    if (kept) {
      const u64 Eq0 = e.eq0[i], Eq1 = e.eq1[i];
      const u64 Xv0 = Eq0 | st.Mv0, Xv1 = Eq1 | st.Mv1;
      const u64 EP0 = Eq0 & st.Pv0, EP1 = Eq1 & st.Pv1;
      const u64 sA = EP0 + st.Pv0;
      const u64 sB = EP1 + st.Pv1 + (sA < EP0 ? 1ull : 0ull);
      const u64 Xh0 = (sA ^ st.Pv0) | Eq0;
      const u64 Xh1 = (sB ^ st.Pv1) | Eq1;
      const u64 Ph0 = st.Mv0 | ~(Xh0 | st.Pv0);
      const u64 Ph1 = st.Mv1 | ~(Xh1 | st.Pv1);
      const u64 Mh0 = st.Pv0 & Xh0, Mh1 = st.Pv1 & Xh1;
      st.score += (int)(((hw ? Ph1 : Ph0) & hmask) != 0);
      st.score -= (int)(((hw ? Mh1 : Mh0) & hmask) != 0);
      const u64 nPh1 = (Ph1 << 1) | (Ph0 >> 63);
      const u64 nPh0 = (Ph0 << 1) | 1ull;  // dp[i][0] = i boundary
      const u64 nMh1 = (Mh1 << 1) | (Mh0 >> 63);
      const u64 nMh0 = (Mh0 << 1);
      st.Pv0 = nMh0 | ~(Xv0 | nPh0);
      st.Pv1 = nMh1 | ~(Xv1 | nPh1);
      st.Mv0 = nPh0 & Xv0;
      st.Mv1 = nPh1 & Xv1;
    }
  }
}

__global__ __launch_bounds__(64) void k_dp(
    const int2* __restrict__ tl,
    const int* __restrict__ elen, const int* __restrict__ labels,
    const int* __restrict__ llen,
    float* __restrict__ wer, float* __restrict__ logp_out) {
  __shared__ uint32_t pq[4][NV];  // [word-half][token], 2 KB, bank = c%32
  const int b = blockIdx.x;
  const int tid = threadIdx.x;
  const int m = llen[b];  // ref_len in [80,100], uniform
  {
    const int* __restrict__ lab = labels + b * 100;  // L == 100
    const int e0 = m < 32 ? m : 32, e1 = m < 64 ? m : 64;
    const int e2 = m < 96 ? m : 96, e3 = m;
#pragma unroll
    for (int h = 0; h < 2; h++) {   // thread builds columns tid and tid+64
      const int c = tid + h * 64;
      uint32_t a0 = 0, a1 = 0, a2 = 0, a3 = 0;
      for (int i = 0; i < e0; i++)  a0 |= (uint32_t)(lab[i] == c) << i;
      for (int i = 32; i < e1; i++) a1 |= (uint32_t)(lab[i] == c) << (i - 32);
      for (int i = 64; i < e2; i++) a2 |= (uint32_t)(lab[i] == c) << (i - 64);
      for (int i = 96; i < e3; i++) a3 |= (uint32_t)(lab[i] == c) << (i - 96);
      pq[0][c] = a0; pq[1][c] = a1; pq[2][c] = a2; pq[3][c] = a3;
    }
  }
  __syncthreads();
  const bool active = (tid < 50);
  const int lane = active ? tid : 49;
  const int pa = b * NP + lane;        // path A
  const int pb = pa + 50;              // path B
  const int myel = elen[b];            // uniform
  const int ntiles = (myel + TILE - 1) / TILE;  // >= 100 always

  DpState sA, sB;
  sA.Pv0 = ~0ull; sA.Pv1 = ~0ull; sA.Mv0 = 0ull; sA.Mv1 = 0ull;
  sA.score = m; sA.prev = -1; sA.logp = 0.0;
  sB = sA;
  const int hw = (m - 1) >> 6;
  const u64 hmask = 1ull << ((m - 1) & 63);

  int2 a0[TILE], b0[TILE], a1[TILE], b1[TILE];
  Ext eAa, eAb, eBa, eBb;
  load4(a0, 0, tl, pa); load4(b0, 0, tl, pb);
  load4(a1, 1, tl, pa); load4(b1, 1, tl, pb);
  extract4(a0, pq, eAa); extract4(b0, pq, eAb);
  for (int tile = 0; tile < ntiles; tile += 2) {
    if (tile + 2 < ntiles) { load4(a0, tile + 2, tl, pa); load4(b0, tile + 2, tl, pb); }
    extract4(a1, pq, eBa); extract4(b1, pq, eBb);
    proc4(eAa, tile, myel, hw, hmask, sA);     // two independent chains ->
    proc4(eAb, tile, myel, hw, hmask, sB);     // scheduler interleaves (ILP-2)
    if (tile + 3 < ntiles) { load4(a1, tile + 3, tl, pa); load4(b1, tile + 3, tl, pb); }
    if (tile + 2 < ntiles) { extract4(a0, pq, eAa); extract4(b0, pq, eAb); }
    if (tile + 1 < ntiles) {
      proc4(eBa, tile + 1, myel, hw, hmask, sA);
      proc4(eBb, tile + 1, myel, hw, hmask, sB);
    }
  }
  if (active) {
    wer[pa] = (float)sA.score; logp_out[pa] = (float)sA.logp;
    wer[pb] = (float)sB.score; logp_out[pb] = (float)sB.logp;
  }
}

// ---------------- Kernel 3: per-b softmax over P, expected WER, mean -----------
__global__ __launch_bounds__(512) void k_final(
    const float* __restrict__ wer, const float* __restrict__ logp,
    float* __restrict__ out) {
  __shared__ float partial[NB];
  const int w = threadIdx.x >> 6, lane = threadIdx.x & 63;
  const int base = w * NP;
  float l0 = (lane < NP) ? logp[base + lane] : -1e30f;
  float l1 = (lane + 64 < NP) ? logp[base + lane + 64] : -1e30f;
  float mx = fmaxf(l0, l1);
  for (int off = 1; off < 64; off <<= 1) mx = fmaxf(mx, __shfl_xor(mx, off));
  const float e0 = (lane < NP) ? __expf(l0 - mx) : 0.0f;
  const float e1 = (lane + 64 < NP) ? __expf(l1 - mx) : 0.0f;
  const float w0 = (lane < NP) ? wer[base + lane] : 0.0f;
  const float w1 = (lane + 64 < NP) ? wer[base + lane + 64] : 0.0f;
  float s = e0 + e1;
  float a = e0 * w0 + e1 * w1;
  for (int off = 1; off < 64; off <<= 1) {
    s += __shfl_xor(s, off);
    a += __shfl_xor(a, off);
  }
  if (lane == 0) partial[w] = a / s;
  __syncthreads();
  if (threadIdx.x == 0) {
    float tot = 0.0f;
    for (int i = 0; i < NB; i++) tot += partial[i];
    out[0] = tot * (1.0f / (float)NBP);
  }
}

extern "C" void kernel_launch(void* const* d_in, const int* in_sizes, int n_in,
                              void* d_out, int out_size, void* d_ws, size_t ws_size,
                              hipStream_t stream) {
  const float* em     = (const float*)d_in[0];
  const int*   elen   = (const int*)d_in[1];
  const int*   labels = (const int*)d_in[2];
  const int*   llen   = (const int*)d_in[3];
  float* out = (float*)d_out;
  char* ws = (char*)d_ws;
  int2*  tlb  = (int2*)ws;                                  // 500*800*8 = 3.2 MB
  float* wer  = (float*)(ws + (size_t)NT * NBP * 8);        // 3.2 KB
  float* logp = (float*)(ws + (size_t)NT * NBP * 8 + NBP * 4);

  k_sample<<<dim3(NB * NT * 50 / 64), dim3(64), 0, stream>>>(em, elen, tlb);
  k_dp<<<dim3(NB), dim3(64), 0, stream>>>(tlb, elen, labels, llen, wer, logp);
  k_final<<<dim3(1), dim3(512), 0, stream>>>(wer, logp, out);
}

// Round 8
// 258.880 us; speedup vs baseline: 1.2578x; 1.2578x over previous
//
#include <hip/hip_runtime.h>
#include <stdint.h>

#define NB 8
#define NP 100
#define NT 500
#define NV 128
#define NBP 800   // NB*NP
#define TS 512    // per-path stream stride (tok2 u8 / lp2 f32)

typedef unsigned long long u64;

// rotl via single v_alignbit_b32: alignbit(x,x,32-r) = rotr(x,32-r) = rotl(x,r)
#define ROTL(x, r) __builtin_amdgcn_alignbit((x), (x), 32 - (r))

// ---------------- Threefry-2x32, key = (0,1) (jax.random.key(1)) ----------------
__device__ __forceinline__ uint32_t threefry01_lo(uint32_t x0, uint32_t x1) {
  const uint32_t k0 = 0u, k1 = 1u;
  const uint32_t k2 = 0x1BD11BDAu ^ k0 ^ k1;  // 0x1BD11BDB
  x0 += k0; x1 += k1;
#define TF_R(r) { x0 += x1; x1 = ROTL(x1, r); x1 ^= x0; }
  TF_R(13) TF_R(15) TF_R(26) TF_R(6)
  x0 += k1; x1 += k2 + 1u;
  TF_R(17) TF_R(29) TF_R(16) TF_R(24)
  x0 += k2; x1 += k0 + 2u;
  TF_R(13) TF_R(15) TF_R(26) TF_R(6)
  x0 += k0; x1 += k1 + 3u;
  TF_R(17) TF_R(29) TF_R(16) TF_R(24)
  x0 += k1; x1 += k2 + 4u;
  TF_R(13) TF_R(15) TF_R(26) TF_R(6)
  x1 += k0 + 5u;            // x0's final add is dead — only the low word is used
#undef TF_R
  return x1;
}

// ---------------- Kernel 1: Gumbel sampling, argmin over V=128 -----------------
// argmax_v(0.5*e + g_v) == argmin_v((-log2 u_v) * exp(-0.5*e_v)).
// Lane pair (2k, 2k+1) splits the 128-v range (64 each), combined by one
// shfl_xor(1) with exact first-index tiebreak. Thread handles 2 paths (ILP-2).
// Outputs per-path streams: tok2[bp*TS+t] (u8), lp2[bp*TS+t] (f32).
__global__ __launch_bounds__(64) void k_sample(
    const float* __restrict__ em, const int* __restrict__ elen,
    uint8_t* __restrict__ tok2, float* __restrict__ lp2) {
  __shared__ float snw[2][NV + 1];  // -exp2(e * -0.5*log2e), 2 rows
  const int tid = threadIdx.x;
  const int item0 = blockIdx.x * 32;          // (R,pp) item index = g>>1
  const int R0 = item0 / 50;
  for (int i = tid; i < 2 * NV; i += 64) {    // stage 2 rows
    const int r = i >> 7, v = i & 127;
    int R = R0 + r; R = R < NB * NT ? R : NB * NT - 1;
    snw[r][v] = -__builtin_amdgcn_exp2f(em[(size_t)R * NV + v] * -0.7213475204444817f);
  }
  __syncthreads();
  const int g = blockIdx.x * 64 + tid;
  const int item = g >> 1, half = g & 1;
  const int R = item / 50;
  const int pp = item - R * 50;
  const int b = R / NT;
  const int t = R - b * NT;
  if (t >= elen[b]) return;  // frames beyond length never consumed (pairs exit together)
  const int r = R - R0;
  const int vh = half << 6;
  const int bp0 = b * NP + 2 * pp;
  const uint32_t base0 = ((uint32_t)(bp0 * NT + t) << 7) + (uint32_t)vh;
  const uint32_t base1 = base0 + (uint32_t)(NT << 7);   // path +1
  const float span = (float)(1.0 - 1e-6) - 1e-6f;
  float best0 = 3.0e38f, best1 = 3.0e38f;
  int bi0 = 0, bi1 = 0;
#pragma unroll 8
  for (int i = 0; i < 64; i++) {
    // partitionable threefry: bits[idx] = low output of threefry(key, idx>>32, idx)
    const uint32_t r0 = threefry01_lo(0u, base0 + (uint32_t)i);
    const uint32_t r1 = threefry01_lo(0u, base1 + (uint32_t)i);
    const float f0 = __uint_as_float((r0 >> 9) | 0x3f800000u) - 1.0f;
    const float f1 = __uint_as_float((r1 >> 9) | 0x3f800000u) - 1.0f;
    const float u0 = fmaf(f0, span, 1e-6f);   // clamp dropped: fma >= 1e-6 always
    const float u1 = fmaf(f1, span, 1e-6f);
    const float w = snw[r][vh + i];
    const float s0 = __log2f(u0) * w;         // (-log2 u) * exp(-e/2) > 0
    const float s1 = __log2f(u1) * w;
    if (s0 < best0) { best0 = s0; bi0 = vh + i; }  // strict < = first-index tiebreak
    if (s1 < best1) { best1 = s1; bi1 = vh + i; }
  }
  // combine the two halves (partner lane): lower score wins, tie -> lower v
  {
    const float ob = __shfl_xor(best0, 1); const int oi = __shfl_xor(bi0, 1);
    if (ob < best0 || (ob == best0 && oi < bi0)) { best0 = ob; bi0 = oi; }
    const float ob1 = __shfl_xor(best1, 1); const int oi1 = __shfl_xor(bi1, 1);
    if (ob1 < best1 || (ob1 == best1 && oi1 < bi1)) { best1 = ob1; bi1 = oi1; }
  }
  if (half == 0) {
    const float e0 = em[(size_t)R * NV + bi0];
    const float e1 = em[(size_t)R * NV + bi1];
    tok2[(size_t)bp0 * TS + t] = (uint8_t)bi0;
    tok2[(size_t)(bp0 + 1) * TS + t] = (uint8_t)bi1;
    lp2[(size_t)bp0 * TS + t] = e0;
    lp2[(size_t)(bp0 + 1) * TS + t] = e1;
  }
}

// ---------------- Kernel 2: CTC collapse + Myers bit-parallel edit distance ----
// one block per b (8 x 128), lane = path (active < 100). Tokens come from the
// per-path u8 stream: 1x 8B load per 8 frames, 32-frame register lookahead
// (covers ~1900cy >> HBM latency). eq-extract pipelined one 4-frame half ahead.
struct Eq4 { u64 e0[4], e1[4]; int cc[4]; };

__device__ __forceinline__ void ext4(uint32_t wbits, const uint32_t* __restrict__ pqf,
                                     Eq4& E) {
#pragma unroll
  for (int i = 0; i < 4; i++) {
    const int byte = (wbits >> (8 * i)) & 255;
    const int c = byte & 127;          // in-bounds even for garbage frames
    E.cc[i] = byte;
    E.e0[i] = (u64)pqf[c] | ((u64)pqf[128 + c] << 32);
    E.e1[i] = (u64)pqf[256 + c] | ((u64)pqf[384 + c] << 32);
  }
}

__device__ __forceinline__ void proc4(const Eq4& E, int fbase, int myel,
                                      int hw, u64 hmask,
                                      u64& Pv0, u64& Pv1, u64& Mv0, u64& Mv1,
                                      int& score, int& prev) {
#pragma unroll
  for (int i = 0; i < 4; i++) {
    if (fbase + i >= myel) break;  // uniform per block
    const int c = E.cc[i];
    const bool kept = (c != 0) && (c != prev);
    prev = c;
    if (kept) {
      const u64 Eq0 = E.e0[i], Eq1 = E.e1[i];
      const u64 Xv0 = Eq0 | Mv0, Xv1 = Eq1 | Mv1;
      const u64 EP0 = Eq0 & Pv0, EP1 = Eq1 & Pv1;
      const u64 sA = EP0 + Pv0;
      const u64 sB = EP1 + Pv1 + (sA < EP0 ? 1ull : 0ull);
      const u64 Xh0 = (sA ^ Pv0) | Eq0;
      const u64 Xh1 = (sB ^ Pv1) | Eq1;
      const u64 Ph0 = Mv0 | ~(Xh0 | Pv0);
      const u64 Ph1 = Mv1 | ~(Xh1 | Pv1);
      const u64 Mh0 = Pv0 & Xh0, Mh1 = Pv1 & Xh1;
      score += (int)(((hw ? Ph1 : Ph0) & hmask) != 0);
      score -= (int)(((hw ? Mh1 : Mh0) & hmask) != 0);
      const u64 nPh1 = (Ph1 << 1) | (Ph0 >> 63);
      const u64 nPh0 = (Ph0 << 1) | 1ull;  // dp[i][0] = i boundary
      const u64 nMh1 = (Mh1 << 1) | (Mh0 >> 63);
      const u64 nMh0 = (Mh0 << 1);
      Pv0 = nMh0 | ~(Xv0 | nPh0);
      Pv1 = nMh1 | ~(Xv1 | nPh1);
      Mv0 = nPh0 & Xv0;
      Mv1 = nPh1 & Xv1;
    }
  }
}

__global__ __launch_bounds__(128) void k_dp(
    const uint8_t* __restrict__ tok2,
    const int* __restrict__ elen, const int* __restrict__ labels,
    const int* __restrict__ llen, float* __restrict__ wer) {
  __shared__ uint32_t pq[4][NV];  // [word-half][token], 2 KB, bank = c%32
  const int b = blockIdx.x;
  const int tid = threadIdx.x;
  const int m = llen[b];  // ref_len in [80,100], uniform
  {
    const int c = tid;    // 128 threads -> one token column each
    const int* __restrict__ lab = labels + b * 100;  // L == 100
    uint32_t a0 = 0, a1 = 0, a2 = 0, a3 = 0;
    const int e0 = m < 32 ? m : 32, e1 = m < 64 ? m : 64;
    const int e2 = m < 96 ? m : 96, e3 = m;
    for (int i = 0; i < e0; i++)  a0 |= (uint32_t)(lab[i] == c) << i;
    for (int i = 32; i < e1; i++) a1 |= (uint32_t)(lab[i] == c) << (i - 32);
    for (int i = 64; i < e2; i++) a2 |= (uint32_t)(lab[i] == c) << (i - 64);
    for (int i = 96; i < e3; i++) a3 |= (uint32_t)(lab[i] == c) << (i - 96);
    pq[0][c] = a0; pq[1][c] = a1; pq[2][c] = a2; pq[3][c] = a3;
  }
  __syncthreads();
  const uint32_t* __restrict__ pqf = &pq[0][0];
  const bool active = (tid < NP);
  const int p = active ? tid : NP - 1;
  const uint8_t* __restrict__ tp = tok2 + ((size_t)(b * NP + p) * TS);
  const int myel = elen[b];  // uniform
  u64 Pv0 = ~0ull, Pv1 = ~0ull, Mv0 = 0ull, Mv1 = 0ull;
  int score = m, prev = -1;
  const int hw = (m - 1) >> 6;
  const u64 hmask = 1ull << ((m - 1) & 63);

  uint2 c0 = *(const uint2*)(tp);        // frames 0..7
  uint2 c1 = *(const uint2*)(tp + 8);
  uint2 c2 = *(const uint2*)(tp + 16);
  uint2 c3 = *(const uint2*)(tp + 24);
  Eq4 A, B;
  ext4(c0.x, pqf, A);
  int f = 0;
  for (int chunk = 0; chunk < TS; chunk += 32) {
    if (f >= myel) break;  // uniform
    uint2 d0, d1, d2, d3;
    const int nxt = chunk + 32;
    if (nxt < TS) {        // harmless over-read of next row handled by guards
      d0 = *(const uint2*)(tp + nxt);
      d1 = *(const uint2*)(tp + nxt + 8);
      d2 = *(const uint2*)(tp + nxt + 16);
      d3 = *(const uint2*)(tp + nxt + 24);
    } else { d0 = c0; d1 = c1; d2 = c2; d3 = c3; }
    ext4(c0.y, pqf, B); proc4(A, f, myel, hw, hmask, Pv0, Pv1, Mv0, Mv1, score, prev); f += 4;
    ext4(c1.x, pqf, A); proc4(B, f, myel, hw, hmask, Pv0, Pv1, Mv0, Mv1, score, prev); f += 4;
    ext4(c1.y, pqf, B); proc4(A, f, myel, hw, hmask, Pv0, Pv1, Mv0, Mv1, score, prev); f += 4;
    ext4(c2.x, pqf, A); proc4(B, f, myel, hw, hmask, Pv0, Pv1, Mv0, Mv1, score, prev); f += 4;
    ext4(c2.y, pqf, B); proc4(A, f, myel, hw, hmask, Pv0, Pv1, Mv0, Mv1, score, prev); f += 4;
    ext4(c3.x, pqf, A); proc4(B, f, myel, hw, hmask, Pv0, Pv1, Mv0, Mv1, score, prev); f += 4;
    ext4(c3.y, pqf, B); proc4(A, f, myel, hw, hmask, Pv0, Pv1, Mv0, Mv1, score, prev); f += 4;
    ext4(d0.x, pqf, A); proc4(B, f, myel, hw, hmask, Pv0, Pv1, Mv0, Mv1, score, prev); f += 4;
    c0 = d0; c1 = d1; c2 = d2; c3 = d3;
  }
  if (active) wer[b * NP + p] = (float)score;
}

// ---------------- Kernel 3: per-b logp row-sums + softmax + expected WER -------
__global__ __launch_bounds__(256) void k_red(
    const float* __restrict__ lp2, const float* __restrict__ wer,
    const int* __restrict__ elen, float* __restrict__ partial) {
  __shared__ float slp[NP];
  const int b = blockIdx.x;
  const int w = threadIdx.x >> 6, lane = threadIdx.x & 63;
  const int el = elen[b];  // uniform
  for (int p = w; p < NP; p += 4) {
    const float* __restrict__ row = lp2 + (size_t)(b * NP + p) * TS;
    double s = 0.0;
    for (int t = lane; t < el; t += 64) s += (double)row[t];  // coalesced
    for (int off = 1; off < 64; off <<= 1) s += __shfl_xor(s, off);
    if (lane == 0) slp[p] = (float)s;
  }
  __syncthreads();
  if (w == 0) {
    const float l0 = (lane < NP) ? slp[lane] : -1e30f;
    const float l1 = (lane + 64 < NP) ? slp[lane + 64] : -1e30f;
    float mx = fmaxf(l0, l1);
    for (int off = 1; off < 64; off <<= 1) mx = fmaxf(mx, __shfl_xor(mx, off));
    const float e0 = (lane < NP) ? __expf(l0 - mx) : 0.0f;
    const float e1 = (lane + 64 < NP) ? __expf(l1 - mx) : 0.0f;
    const float w0 = (lane < NP) ? wer[b * NP + lane] : 0.0f;
    const float w1 = (lane + 64 < NP) ? wer[b * NP + lane + 64] : 0.0f;
    float s = e0 + e1;
    float a = e0 * w0 + e1 * w1;
    for (int off = 1; off < 64; off <<= 1) {
      s += __shfl_xor(s, off);
      a += __shfl_xor(a, off);
    }
    if (lane == 0) partial[b] = a / s;
  }
}

__global__ __launch_bounds__(64) void k_out(
    const float* __restrict__ partial, float* __restrict__ out) {
  if (threadIdx.x == 0) {
    float t = 0.0f;
    for (int i = 0; i < NB; i++) t += partial[i];
    out[0] = t * (1.0f / (float)NBP);
  }
}

extern "C" void kernel_launch(void* const* d_in, const int* in_sizes, int n_in,
                              void* d_out, int out_size, void* d_ws, size_t ws_size,
                              hipStream_t stream) {
  const float* em     = (const float*)d_in[0];
  const int*   elen   = (const int*)d_in[1];
  const int*   labels = (const int*)d_in[2];
  const int*   llen   = (const int*)d_in[3];
  float* out = (float*)d_out;
  char* ws = (char*)d_ws;
  uint8_t* tok2 = (uint8_t*)ws;                                   // 800*512   = 409.6 KB
  float* lp2    = (float*)(ws + (size_t)NBP * TS);                // 800*512*4 = 1.64 MB
  float* wer    = (float*)(ws + (size_t)NBP * TS * 5);            // 3.2 KB
  float* part   = (float*)(ws + (size_t)NBP * TS * 5 + NBP * 4);  // 32 B

  k_sample<<<dim3(NB * NT * 50 * 2 / 64), dim3(64), 0, stream>>>(em, elen, tok2, lp2);
  k_dp<<<dim3(NB), dim3(128), 0, stream>>>(tok2, elen, labels, llen, wer);
  k_red<<<dim3(NB), dim3(256), 0, stream>>>(lp2, wer, elen, part);
  k_out<<<dim3(1), dim3(64), 0, stream>>>(part, out);
}

// Round 9
// 213.899 us; speedup vs baseline: 1.5223x; 1.2103x over previous
//
#include <hip/hip_runtime.h>
#include <stdint.h>

#define NB 8
#define NP 100
#define NT 500
#define NV 128
#define NBP 800        // NB*NP
#define TS 512         // per-path stream stride (tok2 u8 / lp2 f32)
#define NITEMS (NB * NT * 50)  // 200000 items; item = (row R, path-pair pp)
#define ROWD 129       // LDS token row stride in dwords (128 + 1 pad)

typedef unsigned long long u64;

// rotl via single v_alignbit_b32: alignbit(x,x,32-r) = rotr(x,32-r) = rotl(x,r)
#define ROTL(x, r) __builtin_amdgcn_alignbit((x), (x), 32 - (r))

// ---------------- Threefry-2x32, key = (0,1) (jax.random.key(1)) ----------------
__device__ __forceinline__ uint32_t threefry01_lo(uint32_t x0, uint32_t x1) {
  const uint32_t k0 = 0u, k1 = 1u;
  const uint32_t k2 = 0x1BD11BDAu ^ k0 ^ k1;  // 0x1BD11BDB
  x0 += k0; x1 += k1;
#define TF_R(r) { x0 += x1; x1 = ROTL(x1, r); x1 ^= x0; }
  TF_R(13) TF_R(15) TF_R(26) TF_R(6)
  x0 += k1; x1 += k2 + 1u;
  TF_R(17) TF_R(29) TF_R(16) TF_R(24)
  x0 += k2; x1 += k0 + 2u;
  TF_R(13) TF_R(15) TF_R(26) TF_R(6)
  x0 += k0; x1 += k1 + 3u;
  TF_R(17) TF_R(29) TF_R(16) TF_R(24)
  x0 += k1; x1 += k2 + 4u;
  TF_R(13) TF_R(15) TF_R(26) TF_R(6)
  x1 += k0 + 5u;            // x0's final add is dead — only the low word is used
#undef TF_R
  return x1;
}

// ---------------- Kernel 1: Gumbel sampling, argmin over V=128 -----------------
// argmax_v(0.5*e + g_v) == argmin_v((-log2 u_v) * exp(-0.5*e_v)).
// Lane pair (2k, 2k+1) splits the 128-v range (64 each), combined by one
// shfl_xor(1) with exact first-index tiebreak. Thread handles 2 paths (ILP-2).
// 256-thr blocks (4 waves) -> higher residency than R8's 1-wave blocks.
__global__ __launch_bounds__(256) void k_sample(
    const float* __restrict__ em, const int* __restrict__ elen,
    uint8_t* __restrict__ tok2, float* __restrict__ lp2) {
  __shared__ float snw[4][NV + 1];  // -exp2(e * -0.5*log2e); block spans <=4 rows
  const int tid = threadIdx.x;
  const int item0 = blockIdx.x * 128;         // 128 items per block
  const int R0 = item0 / 50;
  for (int i = tid; i < 4 * NV; i += 256) {   // stage 4 rows
    const int r = i >> 7, v = i & 127;
    int R = R0 + r; R = R < NB * NT ? R : NB * NT - 1;
    snw[r][v] = -__builtin_amdgcn_exp2f(em[(size_t)R * NV + v] * -0.7213475204444817f);
  }
  __syncthreads();
  const int gg = blockIdx.x * 256 + tid;
  const int item = gg >> 1, half = gg & 1;
  if (item >= NITEMS) return;
  const int R = item / 50;
  const int pp = item - R * 50;
  const int b = R / NT;
  const int t = R - b * NT;
  if (t >= elen[b]) return;  // frames beyond length never consumed (pairs exit together)
  const int r = R - R0;
  const int vh = half << 6;
  const int bp0 = b * NP + 2 * pp;
  const uint32_t base0 = ((uint32_t)(bp0 * NT + t) << 7) + (uint32_t)vh;
  const uint32_t base1 = base0 + (uint32_t)(NT << 7);   // path +1
  const float span = (float)(1.0 - 1e-6) - 1e-6f;
  float best0 = 3.0e38f, best1 = 3.0e38f;
  int bi0 = 0, bi1 = 0;
#pragma unroll 8
  for (int i = 0; i < 64; i++) {
    // partitionable threefry: bits[idx] = low output of threefry(key, idx>>32, idx)
    const uint32_t r0 = threefry01_lo(0u, base0 + (uint32_t)i);
    const uint32_t r1 = threefry01_lo(0u, base1 + (uint32_t)i);
    const float f0 = __uint_as_float((r0 >> 9) | 0x3f800000u) - 1.0f;
    const float f1 = __uint_as_float((r1 >> 9) | 0x3f800000u) - 1.0f;
    const float u0 = fmaf(f0, span, 1e-6f);   // clamp dropped: fma >= 1e-6 always
    const float u1 = fmaf(f1, span, 1e-6f);
    const float w = snw[r][vh + i];
    const float s0 = __log2f(u0) * w;         // (-log2 u) * exp(-e/2) > 0
    const float s1 = __log2f(u1) * w;
    if (s0 < best0) { best0 = s0; bi0 = vh + i; }  // strict < = first-index tiebreak
    if (s1 < best1) { best1 = s1; bi1 = vh + i; }
  }
  // combine the two halves (partner lane): lower score wins, tie -> lower v
  {
    const float ob = __shfl_xor(best0, 1); const int oi = __shfl_xor(bi0, 1);
    if (ob < best0 || (ob == best0 && oi < bi0)) { best0 = ob; bi0 = oi; }
    const float ob1 = __shfl_xor(best1, 1); const int oi1 = __shfl_xor(bi1, 1);
    if (ob1 < best1 || (ob1 == best1 && oi1 < bi1)) { best1 = ob1; bi1 = oi1; }
  }
  if (half == 0) {
    const float e0 = em[(size_t)R * NV + bi0];
    const float e1 = em[(size_t)R * NV + bi1];
    tok2[(size_t)bp0 * TS + t] = (uint8_t)bi0;
    tok2[(size_t)(bp0 + 1) * TS + t] = (uint8_t)bi1;
    lp2[(size_t)bp0 * TS + t] = e0;
    lp2[(size_t)(bp0 + 1) * TS + t] = e1;
  }
}

// ---------------- Kernel 2: CTC collapse + Myers bit-parallel edit distance ----
// one block per b (8 x 128). ALL tokens bulk-staged to LDS first (coalesced,
// 100-deep MLP hides L3 latency once); Myers loop then has ZERO global loads.
// LDS row stride 129 dwords -> token read bank (p+g)%32 = 2-way (free).
struct Eq4 { u64 e0[4], e1[4]; int cc[4]; };

__device__ __forceinline__ void ext4(uint32_t wbits, const uint32_t* __restrict__ pqf,
                                     Eq4& E) {
#pragma unroll
  for (int i = 0; i < 4; i++) {
    const int byte = (wbits >> (8 * i)) & 255;
    const int c = byte & 127;          // in-bounds even for garbage frames
    E.cc[i] = byte;
    E.e0[i] = (u64)pqf[c] | ((u64)pqf[128 + c] << 32);
    E.e1[i] = (u64)pqf[256 + c] | ((u64)pqf[384 + c] << 32);
  }
}

__device__ __forceinline__ void proc4(const Eq4& E, int fbase, int myel,
                                      int hw, u64 hmask,
                                      u64& Pv0, u64& Pv1, u64& Mv0, u64& Mv1,
                                      int& score, int& prev) {
#pragma unroll
  for (int i = 0; i < 4; i++) {
    if (fbase + i >= myel) break;  // uniform per block
    const int c = E.cc[i];
    const bool kept = (c != 0) && (c != prev);
    prev = c;
    if (kept) {
      const u64 Eq0 = E.e0[i], Eq1 = E.e1[i];
      const u64 Xv0 = Eq0 | Mv0, Xv1 = Eq1 | Mv1;
      const u64 EP0 = Eq0 & Pv0, EP1 = Eq1 & Pv1;
      const u64 sA = EP0 + Pv0;
      const u64 sB = EP1 + Pv1 + (sA < EP0 ? 1ull : 0ull);
      const u64 Xh0 = (sA ^ Pv0) | Eq0;
      const u64 Xh1 = (sB ^ Pv1) | Eq1;
      const u64 Ph0 = Mv0 | ~(Xh0 | Pv0);
      const u64 Ph1 = Mv1 | ~(Xh1 | Pv1);
      const u64 Mh0 = Pv0 & Xh0, Mh1 = Pv1 & Xh1;
      score += (int)(((hw ? Ph1 : Ph0) & hmask) != 0);
      score -= (int)(((hw ? Mh1 : Mh0) & hmask) != 0);
      const u64 nPh1 = (Ph1 << 1) | (Ph0 >> 63);
      const u64 nPh0 = (Ph0 << 1) | 1ull;  // dp[i][0] = i boundary
      const u64 nMh1 = (Mh1 << 1) | (Mh0 >> 63);
      const u64 nMh0 = (Mh0 << 1);
      Pv0 = nMh0 | ~(Xv0 | nPh0);
      Pv1 = nMh1 | ~(Xv1 | nPh1);
      Mv0 = nPh0 & Xv0;
      Mv1 = nPh1 & Xv1;
    }
  }
}

__global__ __launch_bounds__(128) void k_dp(
    const uint8_t* __restrict__ tok2,
    const int* __restrict__ elen, const int* __restrict__ labels,
    const int* __restrict__ llen, float* __restrict__ wer) {
  __shared__ uint32_t pq[4][NV];        // 2 KB, bank = c%32
  __shared__ uint32_t tokL[NP * ROWD];  // 51.6 KB token slab
  const int b = blockIdx.x;
  const int tid = threadIdx.x;
  // ---- bulk token staging: 12800 dwords, coalesced, deep MLP ----
  const uint32_t* __restrict__ src = (const uint32_t*)(tok2 + (size_t)b * NP * TS);
#pragma unroll 4
  for (int i = 0; i < 100; i++) {
    const int gi = i * 128 + tid;       // dword index in the slab
    const int row = gi >> 7, col = gi & 127;
    tokL[row * ROWD + col] = src[gi];
  }
  // ---- peq build: thread = token column ----
  const int m = llen[b];  // ref_len in [80,100], uniform
  {
    const int c = tid;
    const int* __restrict__ lab = labels + b * 100;  // L == 100
    uint32_t a0 = 0, a1 = 0, a2 = 0, a3 = 0;
    const int e0 = m < 32 ? m : 32, e1 = m < 64 ? m : 64;
    const int e2 = m < 96 ? m : 96, e3 = m;
    for (int i = 0; i < e0; i++)  a0 |= (uint32_t)(lab[i] == c) << i;
    for (int i = 32; i < e1; i++) a1 |= (uint32_t)(lab[i] == c) << (i - 32);
    for (int i = 64; i < e2; i++) a2 |= (uint32_t)(lab[i] == c) << (i - 64);
    for (int i = 96; i < e3; i++) a3 |= (uint32_t)(lab[i] == c) << (i - 96);
    pq[0][c] = a0; pq[1][c] = a1; pq[2][c] = a2; pq[3][c] = a3;
  }
  __syncthreads();
  const uint32_t* __restrict__ pqf = &pq[0][0];
  const bool active = (tid < NP);
  const int p = active ? tid : NP - 1;
  const uint32_t* __restrict__ tp = tokL + p * ROWD;
  const int myel = elen[b];  // uniform
  u64 Pv0 = ~0ull, Pv1 = ~0ull, Mv0 = 0ull, Mv1 = 0ull;
  int score = m, prev = -1;
  const int hw = (m - 1) >> 6;
  const u64 hmask = 1ull << ((m - 1) & 63);

  const int ng = (myel + 3) >> 2;       // 4-frame groups, <= 125
  Eq4 A, B;
  ext4(tp[0], pqf, A);
  int g = 0;
  for (; g + 1 < ng; g += 2) {
    ext4(tp[g + 1], pqf, B);            // extract next while processing current
    proc4(A, g * 4, myel, hw, hmask, Pv0, Pv1, Mv0, Mv1, score, prev);
    if (g + 2 < ng) ext4(tp[g + 2], pqf, A);
    proc4(B, (g + 1) * 4, myel, hw, hmask, Pv0, Pv1, Mv0, Mv1, score, prev);
  }
  if (g < ng) proc4(A, g * 4, myel, hw, hmask, Pv0, Pv1, Mv0, Mv1, score, prev);
  if (active) wer[b * NP + p] = (float)score;
}

// ---------------- Kernel 3: per-path logp row-sum (wave per row) ---------------
// identical per-row reduction tree as before -> identical rounding.
__global__ __launch_bounds__(256) void k_red(
    const float* __restrict__ lp2, const int* __restrict__ elen,
    float* __restrict__ slp) {
  const int b = blockIdx.x;
  const int p = blockIdx.y * 4 + (threadIdx.x >> 6);
  const int lane = threadIdx.x & 63;
  const int el = elen[b];  // uniform
  const float* __restrict__ row = lp2 + (size_t)(b * NP + p) * TS;
  double s = 0.0;
  for (int t = lane; t < el; t += 64) s += (double)row[t];  // coalesced
  for (int off = 1; off < 64; off <<= 1) s += __shfl_xor(s, off);
  if (lane == 0) slp[b * NP + p] = (float)s;
}

// ---------------- Kernel 4: per-b softmax + expected WER + mean ----------------
__global__ __launch_bounds__(512) void k_fin(
    const float* __restrict__ slp, const float* __restrict__ wer,
    float* __restrict__ out) {
  __shared__ float partial[NB];
  const int w = threadIdx.x >> 6, lane = threadIdx.x & 63;  // w = b
  const int base = w * NP;
  const float l0 = (lane < NP) ? slp[base + lane] : -1e30f;
  const float l1 = (lane + 64 < NP) ? slp[base + lane + 64] : -1e30f;
  float mx = fmaxf(l0, l1);
  for (int off = 1; off < 64; off <<= 1) mx = fmaxf(mx, __shfl_xor(mx, off));
  const float e0 = (lane < NP) ? __expf(l0 - mx) : 0.0f;
  const float e1 = (lane + 64 < NP) ? __expf(l1 - mx) : 0.0f;
  const float w0 = (lane < NP) ? wer[base + lane] : 0.0f;
  const float w1 = (lane + 64 < NP) ? wer[base + lane + 64] : 0.0f;
  float s = e0 + e1;
  float a = e0 * w0 + e1 * w1;
  for (int off = 1; off < 64; off <<= 1) {
    s += __shfl_xor(s, off);
    a += __shfl_xor(a, off);
  }
  if (lane == 0) partial[w] = a / s;
  __syncthreads();
  if (threadIdx.x == 0) {
    float tot = 0.0f;
    for (int i = 0; i < NB; i++) tot += partial[i];
    out[0] = tot * (1.0f / (float)NBP);
  }
}

extern "C" void kernel_launch(void* const* d_in, const int* in_sizes, int n_in,
                              void* d_out, int out_size, void* d_ws, size_t ws_size,
                              hipStream_t stream) {
  const float* em     = (const float*)d_in[0];
  const int*   elen   = (const int*)d_in[1];
  const int*   labels = (const int*)d_in[2];
  const int*   llen   = (const int*)d_in[3];
  float* out = (float*)d_out;
  char* ws = (char*)d_ws;
  uint8_t* tok2 = (uint8_t*)ws;                                   // 800*512 = 409.6 KB
  float* lp2    = (float*)(ws + (size_t)NBP * TS);                // 1.64 MB
  float* wer    = (float*)(ws + (size_t)NBP * TS * 5);            // 3.2 KB
  float* slp    = (float*)(ws + (size_t)NBP * TS * 5 + NBP * 4);  // 3.2 KB

  k_sample<<<dim3((NITEMS * 2 + 255) / 256), dim3(256), 0, stream>>>(em, elen, tok2, lp2);
  k_dp<<<dim3(NB), dim3(128), 0, stream>>>(tok2, elen, labels, llen, wer);
  k_red<<<dim3(NB, 25), dim3(256), 0, stream>>>(lp2, elen, slp);
  k_fin<<<dim3(1), dim3(512), 0, stream>>>(slp, wer, out);
}